// Round 2
// baseline (2906.835 us; speedup 1.0000x reference)
//
#include <hip/hip_runtime.h>
#include <hip/hip_bf16.h>
#include <math.h>

// Problem constants
#define BATCH 32
#define IN_LEN 28
#define NN 2048
#define E 256
#define ND 256
#define H 512
#define N_LAYERS 3
#define OUT_LEN 28
#define M_ROWS (BATCH * NN)   // 65536

// ---------------------------------------------------------------------------
// Kernel 1: ts = flat @ W_ts^T + b_ts ; h = concat([ts, node_emb])
// flat[b,n,l] = x_node[b,l,n,0]
// grid (NN/64, B), block 256
// ---------------------------------------------------------------------------
__global__ __launch_bounds__(256)
void k_ts(const float* __restrict__ x_node, const float* __restrict__ node_emb,
          const float* __restrict__ W_ts, const float* __restrict__ b_ts,
          float* __restrict__ h)
{
    __shared__ float xs[IN_LEN][64];
    const int tid = threadIdx.x;
    const int b   = blockIdx.y;
    const int n0  = blockIdx.x * 64;

    for (int idx = tid; idx < IN_LEN * 64; idx += 256) {
        int l = idx >> 6, i = idx & 63;
        xs[l][i] = x_node[((size_t)b * IN_LEN + l) * NN + n0 + i];
    }
    __syncthreads();

    float w[IN_LEN];
    #pragma unroll
    for (int j = 0; j < IN_LEN; j++) w[j] = W_ts[tid * IN_LEN + j];
    const float bias = b_ts[tid];

    for (int i = 0; i < 64; i++) {
        float acc = bias;
        #pragma unroll
        for (int j = 0; j < IN_LEN; j++) acc += xs[j][i] * w[j];
        size_t row = (size_t)b * NN + n0 + i;
        h[row * H + tid]       = acc;
        h[row * H + E + tid]   = node_emb[(size_t)(n0 + i) * ND + tid];
    }
}

// ---------------------------------------------------------------------------
// Kernel 2: tiled SGEMM  C[r,o] = sum_i A[r,i] * W[o,i]  (A: rows x 512, W: 512x512)
// MODE 0: Cout = relu(acc + bias)
// MODE 1: Cout = Cres + acc + bias   (in-place residual: Cres == Cout is OK —
//         each element is read then written by exactly one thread; no
//         __restrict__ on Cres/Cout because they alias.)
// 128x128 tile, K-tile 8, 256 threads, 8x8 microtile.
// grid (rows/128, 512/128)
// ---------------------------------------------------------------------------
template <int MODE>
__global__ __launch_bounds__(256)
void k_gemm(const float* __restrict__ A, const float* __restrict__ W,
            const float* __restrict__ bias, const float* Cres,
            float* Cout)
{
    __shared__ float As[8][128];
    __shared__ float Ws[8][128];

    const int tid  = threadIdx.x;
    const int row0 = blockIdx.x * 128;
    const int col0 = blockIdx.y * 128;

    const int lr = tid >> 1;            // 0..127 (tile row for loading)
    const int lk = (tid & 1) * 4;       // 0 or 4 (k offset for loading)

    const int tx = tid & 15, ty = tid >> 4;
    const int m0 = ty * 4, m1 = 64 + ty * 4;
    const int n0 = tx * 4, n1 = 64 + tx * 4;

    float acc[8][8];
    #pragma unroll
    for (int i = 0; i < 8; i++)
        #pragma unroll
        for (int j = 0; j < 8; j++) acc[i][j] = 0.f;

    const float* Aptr = A + (size_t)(row0 + lr) * H + lk;
    const float* Wptr = W + (size_t)(col0 + lr) * H + lk;

    for (int kt = 0; kt < H; kt += 8) {
        float4 av = *(const float4*)(Aptr + kt);
        float4 wv = *(const float4*)(Wptr + kt);
        __syncthreads();
        As[lk + 0][lr] = av.x; As[lk + 1][lr] = av.y;
        As[lk + 2][lr] = av.z; As[lk + 3][lr] = av.w;
        Ws[lk + 0][lr] = wv.x; Ws[lk + 1][lr] = wv.y;
        Ws[lk + 2][lr] = wv.z; Ws[lk + 3][lr] = wv.w;
        __syncthreads();
        #pragma unroll
        for (int k = 0; k < 8; k++) {
            float a[8], bfr[8];
            *(float4*)&a[0]   = *(const float4*)&As[k][m0];
            *(float4*)&a[4]   = *(const float4*)&As[k][m1];
            *(float4*)&bfr[0] = *(const float4*)&Ws[k][n0];
            *(float4*)&bfr[4] = *(const float4*)&Ws[k][n1];
            #pragma unroll
            for (int i = 0; i < 8; i++)
                #pragma unroll
                for (int j = 0; j < 8; j++)
                    acc[i][j] += a[i] * bfr[j];
        }
    }

    // epilogue
    float bv[8];
    #pragma unroll
    for (int j = 0; j < 4; j++) {
        bv[j]     = bias[col0 + n0 + j];
        bv[4 + j] = bias[col0 + n1 + j];
    }
    #pragma unroll
    for (int i = 0; i < 8; i++) {
        int r = row0 + ((i < 4) ? (m0 + i) : (m1 + i - 4));
        float4 v0, v1;
        if (MODE == 0) {
            v0.x = fmaxf(acc[i][0] + bv[0], 0.f);
            v0.y = fmaxf(acc[i][1] + bv[1], 0.f);
            v0.z = fmaxf(acc[i][2] + bv[2], 0.f);
            v0.w = fmaxf(acc[i][3] + bv[3], 0.f);
            v1.x = fmaxf(acc[i][4] + bv[4], 0.f);
            v1.y = fmaxf(acc[i][5] + bv[5], 0.f);
            v1.z = fmaxf(acc[i][6] + bv[6], 0.f);
            v1.w = fmaxf(acc[i][7] + bv[7], 0.f);
        } else {
            float4 r0 = *(const float4*)&Cres[(size_t)r * H + col0 + n0];
            float4 r1 = *(const float4*)&Cres[(size_t)r * H + col0 + n1];
            v0.x = (r0.x + acc[i][0]) + bv[0];
            v0.y = (r0.y + acc[i][1]) + bv[1];
            v0.z = (r0.z + acc[i][2]) + bv[2];
            v0.w = (r0.w + acc[i][3]) + bv[3];
            v1.x = (r1.x + acc[i][4]) + bv[4];
            v1.y = (r1.y + acc[i][5]) + bv[5];
            v1.z = (r1.z + acc[i][6]) + bv[6];
            v1.w = (r1.w + acc[i][7]) + bv[7];
        }
        *(float4*)&Cout[(size_t)r * H + col0 + n0] = v0;
        *(float4*)&Cout[(size_t)r * H + col0 + n1] = v1;
    }
}

// ---------------------------------------------------------------------------
// Kernel 3: b = sigmoid(h @ Wb^T + bb), g = sigmoid(h @ Wg^T + bg)
// one wave per row; block 256 = 4 rows
// ---------------------------------------------------------------------------
__global__ __launch_bounds__(256)
void k_head(const float* __restrict__ h,
            const float* __restrict__ Wb, const float* __restrict__ bb,
            const float* __restrict__ Wg, const float* __restrict__ bg,
            float* __restrict__ bArr, float* __restrict__ gArr)
{
    const int lane = threadIdx.x & 63;
    const int row  = blockIdx.x * 4 + (threadIdx.x >> 6);

    const float4* h4  = (const float4*)(h + (size_t)row * H);
    const float4* wb4 = (const float4*)Wb;
    const float4* wg4 = (const float4*)Wg;

    float4 u0 = h4[lane];
    float4 u1 = h4[64 + lane];
    float4 a0 = wb4[lane];
    float4 a1 = wb4[64 + lane];
    float4 c0 = wg4[lane];
    float4 c1 = wg4[64 + lane];

    float sb = u0.x * a0.x + u0.y * a0.y + u0.z * a0.z + u0.w * a0.w
             + u1.x * a1.x + u1.y * a1.y + u1.z * a1.z + u1.w * a1.w;
    float sg = u0.x * c0.x + u0.y * c0.y + u0.z * c0.z + u0.w * c0.w
             + u1.x * c1.x + u1.y * c1.y + u1.z * c1.z + u1.w * c1.w;

    #pragma unroll
    for (int off = 32; off >= 1; off >>= 1) {
        sb += __shfl_xor(sb, off);
        sg += __shfl_xor(sg, off);
    }
    if (lane == 0) {
        bArr[row] = 1.f / (1.f + expf(-(sb + bb[0])));
        gArr[row] = 1.f / (1.f + expf(-(sg + bg[0])));
    }
}

// ---------------------------------------------------------------------------
// Kernel 4: per-(b,n) SIR recurrence. thread per row.
// ---------------------------------------------------------------------------
__global__ __launch_bounds__(256)
void k_sir(const float* __restrict__ x_state,
           const float* __restrict__ bArr, const float* __restrict__ gArr,
           float* __restrict__ out)
{
    const int row = blockIdx.x * 256 + threadIdx.x;   // b*NN + n
    const int bb_ = row / NN;
    const int n   = row % NN;

    const float g = gArr[row];
    const float b = bArr[row];
    const float d = expf(-g);

    // x_state[bb_, t, n, c] at xs[t*NN*3 + c]
    const float* xs = x_state + ((size_t)bb_ * IN_LEN) * (NN * 3) + (size_t)n * 3;

    float x1_prev = xs[1];
    float Ih_prev = x1_prev / g;
    float acc = 0.f;
    #pragma unroll 4
    for (int t = 1; t <= IN_LEN - 1; ++t) {
        float x1 = xs[(size_t)t * (NN * 3) + 1];
        float Ih = x1 / g;
        float Iin = fmaxf(Ih - Ih_prev + x1_prev, 0.f);
        acc = acc * d + Iin;
        Ih_prev = Ih;
        x1_prev = x1;
    }
    float ITm1 = acc * d;                                   // sum w1 * Iin_hist
    float Npop = xs[(size_t)(IN_LEN - 1) * (NN * 3) + 2];
    float RTm1 = Npop - xs[(size_t)(IN_LEN - 2) * (NN * 3) + 0];
    float STm1 = Npop - ITm1 - RTm1;
    float Iin0 = b * STm1 * ITm1 / Npop;
    float S = STm1 - Iin0;
    float I = d * (ITm1 + Iin0);    // == sum w2 * [Iin_hist, Iin0]

    float* op = out + ((size_t)bb_ * OUT_LEN) * NN + n;
    #pragma unroll 4
    for (int k = 0; k < OUT_LEN; k++) {
        float Iin = b * S * I / Npop;
        S = S - Iin;
        float Rin = g * I;
        I = d * (I + Iin);
        op[(size_t)k * NN] = Rin;
    }
}

// ---------------------------------------------------------------------------
extern "C" void kernel_launch(void* const* d_in, const int* in_sizes, int n_in,
                              void* d_out, int out_size, void* d_ws, size_t ws_size,
                              hipStream_t stream)
{
    const float* x_node   = (const float*)d_in[0];
    const float* x_state  = (const float*)d_in[1];
    const float* node_emb = (const float*)d_in[2];
    const float* W_ts     = (const float*)d_in[3];
    const float* b_ts     = (const float*)d_in[4];
    const float* enc_W1   = (const float*)d_in[5];
    const float* enc_b1   = (const float*)d_in[6];
    const float* enc_W2   = (const float*)d_in[7];
    const float* enc_b2   = (const float*)d_in[8];
    const float* Wb       = (const float*)d_in[9];
    const float* bb       = (const float*)d_in[10];
    const float* Wg       = (const float*)d_in[11];
    const float* bg       = (const float*)d_in[12];
    float* out = (float*)d_out;

    // Workspace layout (floats): h [M*H] | bArr [M] | gArr [M] | z [chunk*H]
    // z is sized from the ACTUAL ws_size so we never run off the end of d_ws.
    // The layer is row-wise independent, so z can be a row-chunk buffer.
    const size_t hN  = (size_t)M_ROWS * H;
    float* h    = (float*)d_ws;
    float* bArr = h + hN;
    float* gArr = bArr + M_ROWS;
    float* z    = gArr + M_ROWS;

    const size_t wsFloats = ws_size / sizeof(float);
    const size_t fixed    = hN + 2 * (size_t)M_ROWS;
    size_t zAvail = (wsFloats > fixed) ? (wsFloats - fixed) : 0;
    long long chunkLL = (long long)(zAvail / H) & ~127LL;  // multiple of 128 rows
    int chunk = (chunkLL > M_ROWS) ? M_ROWS : (int)chunkLL;
    if (chunk < 128) chunk = 128;  // last-ditch; needs ~128.5 MB workspace min

    // 1. build h
    k_ts<<<dim3(NN / 64, BATCH), 256, 0, stream>>>(x_node, node_emb, W_ts, b_ts, h);

    // 2. encoder layers (row-chunked so z fits in workspace)
    for (int l = 0; l < N_LAYERS; l++) {
        const float* W1 = enc_W1 + (size_t)l * H * H;
        const float* W2 = enc_W2 + (size_t)l * H * H;
        const float* b1 = enc_b1 + (size_t)l * H;
        const float* b2 = enc_b2 + (size_t)l * H;
        for (int r = 0; r < M_ROWS; r += chunk) {
            int rows = (M_ROWS - r < chunk) ? (M_ROWS - r) : chunk;
            float* hr = h + (size_t)r * H;
            dim3 ggrid(rows / 128, H / 128);
            k_gemm<0><<<ggrid, 256, 0, stream>>>(hr, W1, b1, nullptr, z);
            k_gemm<1><<<ggrid, 256, 0, stream>>>(z, W2, b2, hr, hr);
        }
    }

    // 3. heads
    k_head<<<M_ROWS / 4, 256, 0, stream>>>(h, Wb, bb, Wg, bg, bArr, gArr);

    // 4. SIR recurrence + output
    k_sir<<<M_ROWS / 256, 256, 0, stream>>>(x_state, bArr, gArr, out);
}

// Round 3
// 1236.566 us; speedup vs baseline: 2.3507x; 2.3507x over previous
//
#include <hip/hip_runtime.h>
#include <hip/hip_bf16.h>
#include <math.h>

// Problem constants
#define BATCH 32
#define IN_LEN 28
#define NN 2048
#define E 256
#define H 512
#define N_LAYERS 3
#define OUT_LEN 28
#define M_ROWS (BATCH * NN)   // 65536

typedef unsigned short u16;
typedef unsigned int   u32;
typedef __attribute__((ext_vector_type(8))) short short8;   // 8 bf16 (4 VGPRs)
typedef __attribute__((ext_vector_type(4))) float f32x4;    // MFMA accumulator

// ---- bf16 split helpers (RNE) ----------------------------------------------
__device__ __forceinline__ u16 f2bf(float x) {
    union { float f; u32 u; } v; v.f = x;
    u32 r = (v.u + 0x7FFFu + ((v.u >> 16) & 1u)) >> 16;
    return (u16)r;
}
__device__ __forceinline__ float bf2f(u16 h) {
    union { u32 u; float f; } v; v.u = ((u32)h) << 16;
    return v.f;
}

// async global -> LDS, 16 B per lane. LDS dest = wave-uniform base + lane*16.
__device__ __forceinline__ void gload_lds16(const void* g, void* l) {
    __builtin_amdgcn_global_load_lds(
        (const __attribute__((address_space(1))) void*)g,
        (__attribute__((address_space(3))) void*)l, 16, 0, 0);
}

// ---------------------------------------------------------------------------
// Split an fp32 array into bf16 hi/lo arrays.
// ---------------------------------------------------------------------------
__global__ __launch_bounds__(256)
void k_split(const float* __restrict__ src, u16* __restrict__ hi,
             u16* __restrict__ lo, int n)
{
    int i = blockIdx.x * 256 + threadIdx.x;
    if (i < n) {
        float v = src[i];
        u16 h = f2bf(v);
        hi[i] = h;
        lo[i] = f2bf(v - bf2f(h));
    }
}

// ---------------------------------------------------------------------------
// Kernel 1: ts = flat @ W_ts^T + b_ts ; h = concat([ts, node_emb]) -> split
// ---------------------------------------------------------------------------
__global__ __launch_bounds__(256)
void k_ts(const float* __restrict__ x_node, const float* __restrict__ node_emb,
          const float* __restrict__ W_ts, const float* __restrict__ b_ts,
          u16* __restrict__ hhi, u16* __restrict__ hlo)
{
    __shared__ float xs[IN_LEN][64];
    const int tid = threadIdx.x;
    const int b   = blockIdx.y;
    const int n0  = blockIdx.x * 64;

    for (int idx = tid; idx < IN_LEN * 64; idx += 256) {
        int l = idx >> 6, i = idx & 63;
        xs[l][i] = x_node[((size_t)b * IN_LEN + l) * NN + n0 + i];
    }
    __syncthreads();

    float w[IN_LEN];
    #pragma unroll
    for (int j = 0; j < IN_LEN; j++) w[j] = W_ts[tid * IN_LEN + j];
    const float bias = b_ts[tid];

    for (int i = 0; i < 64; i++) {
        float acc = bias;
        #pragma unroll
        for (int j = 0; j < IN_LEN; j++) acc += xs[j][i] * w[j];
        size_t row = (size_t)b * NN + n0 + i;
        u16 thi = f2bf(acc);
        hhi[row * H + tid] = thi;
        hlo[row * H + tid] = f2bf(acc - bf2f(thi));
        float ev = node_emb[(size_t)(n0 + i) * 256 + tid];
        u16 ehi = f2bf(ev);
        hhi[row * H + E + tid] = ehi;
        hlo[row * H + E + tid] = f2bf(ev - bf2f(ehi));
    }
}

// ---------------------------------------------------------------------------
// Kernel 2: MFMA GEMM with split-bf16 inputs.
//   C[r,o] = sum_k A[r,k]*W[o,k]  via  Ahi*Whi + Ahi*Wlo + Alo*Whi
// MODE 0: out = relu(acc+bias) -> split to OutHi/OutLo
// MODE 1: out = acc + bias + (ResHi+ResLo) -> split (in-place on h OK)
// Tile 128x128, BK=32, 256 thr = 4 waves, each wave 64x64 (4x4 of 16x16x32).
// Staging: global_load_lds width-16; XOR chunk swizzle (on the GLOBAL source
// side, LDS side stays lane-contiguous) turns the 8-way fragment-read bank
// conflict into a free 2-way.
// grid (4 col-blocks fastest for A-stripe L2/L3 reuse, rows/128)
// ---------------------------------------------------------------------------
template <int MODE>
__global__ __launch_bounds__(256)
void k_gemm(const u16* __restrict__ Ahi, const u16* __restrict__ Alo,
            const u16* __restrict__ Whi, const u16* __restrict__ Wlo,
            const float* __restrict__ bias,
            const u16* ResHi, const u16* ResLo,
            u16* OutHi, u16* OutLo)
{
    __shared__ __align__(16) u16 sAhi[128 * 32];
    __shared__ __align__(16) u16 sAlo[128 * 32];
    __shared__ __align__(16) u16 sWhi[128 * 32];
    __shared__ __align__(16) u16 sWlo[128 * 32];

    const int tid  = threadIdx.x;
    const int ln   = tid & 63;
    const int wv   = tid >> 6;
    const int col0 = blockIdx.x * 128;
    const int row0 = blockIdx.y * 128;

    // staging role: wave -> one of the 4 tile arrays
    const u16* gbase;
    u16* lbase;
    int tb;
    if      (wv == 0) { gbase = Ahi; lbase = sAhi; tb = row0; }
    else if (wv == 1) { gbase = Alo; lbase = sAlo; tb = row0; }
    else if (wv == 2) { gbase = Whi; lbase = sWhi; tb = col0; }
    else              { gbase = Wlo; lbase = sWlo; tb = col0; }
    const int srow   = ln >> 2;   // row within 16-row issue group
    const int schunk = ln & 3;    // 8-bf16 chunk within row

    f32x4 acc[4][4];
    #pragma unroll
    for (int i = 0; i < 4; i++)
        #pragma unroll
        for (int j = 0; j < 4; j++)
            acc[i][j] = (f32x4)(0.f);

    const int rbase = (wv & 1) * 64;   // wave's row quadrant
    const int cbase = (wv >> 1) * 64;  // wave's col quadrant

    for (int kt = 0; kt < H; kt += 32) {
        __syncthreads();   // previous compute done reading LDS
        #pragma unroll
        for (int i = 0; i < 8; i++) {
            int row = i * 16 + srow;                 // tile row 0..127
            int sc  = schunk ^ ((row >> 1) & 3);     // source chunk (swizzle)
            const u16* gp = gbase + (size_t)(tb + row) * H + kt + sc * 8;
            gload_lds16(gp, lbase + i * 512);        // 1024 B per wave-issue
        }
        __syncthreads();   // drains vmcnt(0): LDS tiles ready

        short8 ahi[4], alo[4], whi[4], wlo[4];
        #pragma unroll
        for (int t = 0; t < 4; t++) {
            int ra = rbase + t * 16 + (ln & 15);
            int ka = ((ln >> 4) ^ ((ra >> 1) & 3)) * 8;
            ahi[t] = *(const short8*)&sAhi[ra * 32 + ka];
            alo[t] = *(const short8*)&sAlo[ra * 32 + ka];
            int rw = cbase + t * 16 + (ln & 15);
            int kw = ((ln >> 4) ^ ((rw >> 1) & 3)) * 8;
            whi[t] = *(const short8*)&sWhi[rw * 32 + kw];
            wlo[t] = *(const short8*)&sWlo[rw * 32 + kw];
        }
        #pragma unroll
        for (int i = 0; i < 4; i++)
            #pragma unroll
            for (int j = 0; j < 4; j++) {
                acc[i][j] = __builtin_amdgcn_mfma_f32_16x16x32_bf16(ahi[i], whi[j], acc[i][j], 0, 0, 0);
                acc[i][j] = __builtin_amdgcn_mfma_f32_16x16x32_bf16(ahi[i], wlo[j], acc[i][j], 0, 0, 0);
                acc[i][j] = __builtin_amdgcn_mfma_f32_16x16x32_bf16(alo[i], whi[j], acc[i][j], 0, 0, 0);
            }
    }

    // epilogue: C/D layout col=lane&15, row=(lane>>4)*4+reg
    #pragma unroll
    for (int i = 0; i < 4; i++) {
        #pragma unroll
        for (int r = 0; r < 4; r++) {
            int grow = row0 + rbase + i * 16 + (ln >> 4) * 4 + r;
            #pragma unroll
            for (int j = 0; j < 4; j++) {
                int gcol = col0 + cbase + j * 16 + (ln & 15);
                float v = acc[i][j][r] + bias[gcol];
                size_t idx = (size_t)grow * H + gcol;
                if (MODE == 0) {
                    v = fmaxf(v, 0.f);
                } else {
                    v += bf2f(ResHi[idx]) + bf2f(ResLo[idx]);
                }
                u16 hi = f2bf(v);
                OutHi[idx] = hi;
                OutLo[idx] = f2bf(v - bf2f(hi));
            }
        }
    }
}

// ---------------------------------------------------------------------------
// Kernel 3: b = sigmoid(h @ Wb^T), g = sigmoid(h @ Wg^T); h from hi+lo
// one wave per row; block 256 = 4 rows; lane covers cols lane*8..lane*8+7
// ---------------------------------------------------------------------------
__global__ __launch_bounds__(256)
void k_head(const u16* __restrict__ hhi, const u16* __restrict__ hlo,
            const float* __restrict__ Wb, const float* __restrict__ bb,
            const float* __restrict__ Wg, const float* __restrict__ bg,
            float* __restrict__ bArr, float* __restrict__ gArr)
{
    const int lane = threadIdx.x & 63;
    const int row  = blockIdx.x * 4 + (threadIdx.x >> 6);

    uint4 uh = *(const uint4*)(hhi + (size_t)row * H + lane * 8);
    uint4 ul = *(const uint4*)(hlo + (size_t)row * H + lane * 8);
    u32 ph[4] = {uh.x, uh.y, uh.z, uh.w};
    u32 pl[4] = {ul.x, ul.y, ul.z, ul.w};
    float hv[8];
    #pragma unroll
    for (int k = 0; k < 4; k++) {
        hv[2 * k]     = bf2f((u16)(ph[k] & 0xFFFF)) + bf2f((u16)(pl[k] & 0xFFFF));
        hv[2 * k + 1] = bf2f((u16)(ph[k] >> 16))    + bf2f((u16)(pl[k] >> 16));
    }
    float4 wb0 = *(const float4*)(Wb + lane * 8);
    float4 wb1 = *(const float4*)(Wb + lane * 8 + 4);
    float4 wg0 = *(const float4*)(Wg + lane * 8);
    float4 wg1 = *(const float4*)(Wg + lane * 8 + 4);

    float sb = hv[0] * wb0.x + hv[1] * wb0.y + hv[2] * wb0.z + hv[3] * wb0.w
             + hv[4] * wb1.x + hv[5] * wb1.y + hv[6] * wb1.z + hv[7] * wb1.w;
    float sg = hv[0] * wg0.x + hv[1] * wg0.y + hv[2] * wg0.z + hv[3] * wg0.w
             + hv[4] * wg1.x + hv[5] * wg1.y + hv[6] * wg1.z + hv[7] * wg1.w;

    #pragma unroll
    for (int off = 32; off >= 1; off >>= 1) {
        sb += __shfl_xor(sb, off);
        sg += __shfl_xor(sg, off);
    }
    if (lane == 0) {
        bArr[row] = 1.f / (1.f + expf(-(sb + bb[0])));
        gArr[row] = 1.f / (1.f + expf(-(sg + bg[0])));
    }
}

// ---------------------------------------------------------------------------
// Kernel 4: per-(b,n) SIR recurrence. thread per row.
// ---------------------------------------------------------------------------
__global__ __launch_bounds__(256)
void k_sir(const float* __restrict__ x_state,
           const float* __restrict__ bArr, const float* __restrict__ gArr,
           float* __restrict__ out)
{
    const int row = blockIdx.x * 256 + threadIdx.x;   // b*NN + n
    const int bb_ = row / NN;
    const int n   = row % NN;

    const float g = gArr[row];
    const float b = bArr[row];
    const float d = expf(-g);

    const float* xs = x_state + ((size_t)bb_ * IN_LEN) * (NN * 3) + (size_t)n * 3;

    float x1_prev = xs[1];
    float Ih_prev = x1_prev / g;
    float acc = 0.f;
    #pragma unroll 4
    for (int t = 1; t <= IN_LEN - 1; ++t) {
        float x1 = xs[(size_t)t * (NN * 3) + 1];
        float Ih = x1 / g;
        float Iin = fmaxf(Ih - Ih_prev + x1_prev, 0.f);
        acc = acc * d + Iin;
        Ih_prev = Ih;
        x1_prev = x1;
    }
    float ITm1 = acc * d;
    float Npop = xs[(size_t)(IN_LEN - 1) * (NN * 3) + 2];
    float RTm1 = Npop - xs[(size_t)(IN_LEN - 2) * (NN * 3) + 0];
    float STm1 = Npop - ITm1 - RTm1;
    float Iin0 = b * STm1 * ITm1 / Npop;
    float S = STm1 - Iin0;
    float I = d * (ITm1 + Iin0);

    float* op = out + ((size_t)bb_ * OUT_LEN) * NN + n;
    #pragma unroll 4
    for (int k = 0; k < OUT_LEN; k++) {
        float Iin = b * S * I / Npop;
        S = S - Iin;
        float Rin = g * I;
        I = d * (I + Iin);
        op[(size_t)k * NN] = Rin;
    }
}

// ---------------------------------------------------------------------------
extern "C" void kernel_launch(void* const* d_in, const int* in_sizes, int n_in,
                              void* d_out, int out_size, void* d_ws, size_t ws_size,
                              hipStream_t stream)
{
    const float* x_node   = (const float*)d_in[0];
    const float* x_state  = (const float*)d_in[1];
    const float* node_emb = (const float*)d_in[2];
    const float* W_ts     = (const float*)d_in[3];
    const float* b_ts     = (const float*)d_in[4];
    const float* enc_W1   = (const float*)d_in[5];
    const float* enc_b1   = (const float*)d_in[6];
    const float* enc_W2   = (const float*)d_in[7];
    const float* enc_b2   = (const float*)d_in[8];
    const float* Wb       = (const float*)d_in[9];
    const float* bb       = (const float*)d_in[10];
    const float* Wg       = (const float*)d_in[11];
    const float* bg       = (const float*)d_in[12];
    float* out = (float*)d_out;

    // Workspace (bytes): hhi 64M | hlo 64M | wHi 3M | wLo 3M | bArr .25M |
    // gArr .25M | z (chunk*512*2 arrays bf16, sized from ws_size)
    u16* hhi   = (u16*)d_ws;
    u16* hlo   = hhi + (size_t)M_ROWS * H;
    u16* wHi   = hlo + (size_t)M_ROWS * H;          // [6][512][512]
    u16* wLo   = wHi + (size_t)6 * H * H;
    float* bArr = (float*)(wLo + (size_t)6 * H * H);
    float* gArr = bArr + M_ROWS;
    u16* zhi   = (u16*)(gArr + M_ROWS);

    size_t used  = (size_t)((char*)zhi - (char*)d_ws);
    size_t avail = (ws_size > used) ? ws_size - used : 0;
    long long chunkLL = (long long)(avail / (H * 2 * sizeof(u16))) & ~127LL;
    int chunk = (chunkLL > M_ROWS) ? M_ROWS : (int)chunkLL;
    if (chunk < 128) chunk = 128;
    u16* zlo = zhi + (size_t)chunk * H;

    // weight conversion (redone every call; d_ws is re-poisoned)
    const int nW = N_LAYERS * H * H;   // 786432
    k_split<<<nW / 256, 256, 0, stream>>>(enc_W1, wHi, wLo, nW);
    k_split<<<nW / 256, 256, 0, stream>>>(enc_W2, wHi + nW, wLo + nW, nW);

    // 1. build h (split)
    k_ts<<<dim3(NN / 64, BATCH), 256, 0, stream>>>(x_node, node_emb, W_ts, b_ts, hhi, hlo);

    // 2. encoder layers (row-chunked so z fits in workspace)
    for (int l = 0; l < N_LAYERS; l++) {
        const u16* W1hi = wHi + (size_t)l * H * H;
        const u16* W1lo = wLo + (size_t)l * H * H;
        const u16* W2hi = wHi + (size_t)nW + (size_t)l * H * H;
        const u16* W2lo = wLo + (size_t)nW + (size_t)l * H * H;
        const float* b1 = enc_b1 + (size_t)l * H;
        const float* b2 = enc_b2 + (size_t)l * H;
        for (int r = 0; r < M_ROWS; r += chunk) {
            int rows = (M_ROWS - r < chunk) ? (M_ROWS - r) : chunk;
            u16* hrhi = hhi + (size_t)r * H;
            u16* hrlo = hlo + (size_t)r * H;
            dim3 g(4, rows / 128);
            k_gemm<0><<<g, 256, 0, stream>>>(hrhi, hrlo, W1hi, W1lo, b1,
                                             nullptr, nullptr, zhi, zlo);
            k_gemm<1><<<g, 256, 0, stream>>>(zhi, zlo, W2hi, W2lo, b2,
                                             hrhi, hrlo, hrhi, hrlo);
        }
    }

    // 3. heads
    k_head<<<M_ROWS / 4, 256, 0, stream>>>(hhi, hlo, Wb, bb, Wg, bg, bArr, gArr);

    // 4. SIR recurrence + output
    k_sir<<<M_ROWS / 256, 256, 0, stream>>>(x_state, bArr, gArr, out);
}